// Round 1
// baseline (236.887 us; speedup 1.0000x reference)
//
#include <hip/hip_runtime.h>
#include <math.h>

// Problem constants
#define KCODES 1024
#define DDIM   64

// Output layout (floats), concatenated in reference return order:
// z_q_out [16,64,64,64], idx_out [16,64,64], emb_new [64,1024],
// emb_ema_new [64,1024], counts_ema_new [1024]
constexpr size_t O_ZQ  = 0;
constexpr size_t O_IDX = 4194304;
constexpr size_t O_EMB = O_IDX + 65536;   // 4259840
constexpr size_t O_EMA = O_EMB + 65536;   // 4325376
constexpr size_t O_CEN = O_EMA + 65536;   // 4390912

// Workspace layout (float offsets)
constexpr size_t W_UPD   = 0;               // [K][D] segment-sum accumulator
constexpr size_t W_CNT   = 65536;           // [K] histogram
constexpr size_t W_ENORM = W_CNT + 1024;    // [K] ||e_k||^2
constexpr size_t W_EMBT  = W_ENORM + 1024;  // [K][D] transposed codebook fp32
constexpr size_t W_E16   = W_EMBT + 65536;  // [K][D] transposed codebook fp16 (32768 floats)
constexpr size_t W_FLAGN = W_E16 + 32768;   // 1 int: count of ambiguous rows (+pad)
constexpr size_t W_FLAGL = W_FLAGN + 16;    // [65536] int row ids

typedef _Float16 f16;
typedef f16 f16x8 __attribute__((ext_vector_type(8)));
typedef float f32x4 __attribute__((ext_vector_type(4)));

// ---------------------------------------------------------------------------
// K1: LDS-tiled transpose emb[D][K] -> embT[K][D] (fp32 + fp16), eNorm,
// zero W_UPD/W_CNT/flag counter. 16 blocks; block g handles codes g*64..+63.
__global__ __launch_bounds__(256) void vq_prep(const float* __restrict__ emb,
                                               float* __restrict__ ws) {
  __shared__ float t_lds[64 * 65];          // [d][k] padded (+1)
  const int tid = threadIdx.x;
  const int g   = blockIdx.x;
  const int k0  = g * 64;

  #pragma unroll
  for (int it = 0; it < 16; ++it) {
    const int idx = tid + it * 256;         // 0..4095
    const int d   = idx >> 6;
    const int kq  = idx & 63;
    t_lds[d * 65 + kq] = emb[d * KCODES + k0 + kq];
  }
  __syncthreads();

  f16* e16p = (f16*)(ws + W_E16);
  #pragma unroll
  for (int it = 0; it < 16; ++it) {
    const int idx = tid + it * 256;
    const int k   = idx >> 6;
    const int d   = idx & 63;
    const float v = t_lds[d * 65 + k];
    ws[W_EMBT + (size_t)(k0 + k) * 64 + d] = v;
    e16p[(size_t)(k0 + k) * 64 + d] = (f16)v;   // plain [code][d] fp16
  }

  if (tid < 64) {
    const int k = tid;
    float s = 0.f;
    #pragma unroll
    for (int d = 0; d < DDIM; ++d) {
      const float v = t_lds[d * 65 + k];
      s = fmaf(v, v, s);
    }
    ws[W_ENORM + k0 + k] = s;
  }

  float4* u4 = (float4*)(ws + W_UPD);
  #pragma unroll
  for (int j = 0; j < 4; ++j) u4[g * 1024 + tid + j * 256] = float4{0.f, 0.f, 0.f, 0.f};
  if (tid < 64) ws[W_CNT + k0 + tid] = 0.f;
  if (g == 0 && tid == 0) ((int*)(ws + W_FLAGN))[0] = 0;
}

// ---------------------------------------------------------------------------
// K2: MFMA distance GEMM + certified argmin + fused epilogue.
// 1024 blocks x 256 threads; block = 64 rows x full K.
// Per wave: 16 rows. A = codes (fp16 embT, LDS, XOR-swizzled 16B units),
// B = z rows (fp16 in regs, built once), C[code][row]: col=lane&15=row,
// code=(lane>>4)*4+reg (m89 layout). D=64 -> 2 chained mfma_16x16x32_f16.
// Margin certificate: f16 products are exact in fp32; error <= 1.01*2^-10 *
// ||z||*Emax per distance. Accept argmin iff m2-m1 > 2^-8*||z||*Emax (4x 2B);
// else append row to rescore list (exact fp32 pass in K3).
#define ZP 68
__global__ __launch_bounds__(256, 4) void vq_main(
    const float* __restrict__ z_e,
    const float* __restrict__ e16gf,  // ws + W_E16 (fp16 [K][64])
    const float* __restrict__ embT,   // ws + W_EMBT [K][D] fp32 (epilogue A)
    const float* __restrict__ eN,     // ws + W_ENORM [K]
    float* __restrict__ upd,          // ws + W_UPD   [K][D]
    float* __restrict__ cnt,          // ws + W_CNT   [K]
    int*   __restrict__ flagn,
    int*   __restrict__ flagl,
    float* __restrict__ out) {
  __shared__ float z_lds[DDIM * ZP];            // [d][row] padded, fp32
  __shared__ __align__(16) f16 e_lds[128 * 64]; // chunk of 128 codes, swizzled
  __shared__ __align__(16) float en_lds[128];
  __shared__ int   bidx[64];
  __shared__ float sred[33];

  const int tid  = threadIdx.x;
  const int bid  = blockIdx.x;
  const int wv   = tid >> 6;
  const int lane = tid & 63;
  const int m    = lane & 15;        // A-row supplier / C col (z row)
  const int q    = lane >> 4;        // k-subgroup / C code-subgroup
  const int rloc = wv * 16 + m;      // this lane's z row within block

  const int n0  = bid * 64;
  const int b   = n0 >> 12;
  const int hw0 = n0 & 4095;
  const size_t zbase = (size_t)b * 262144 + (size_t)hw0;

  // ---- stage z tile [64d][64r] fp32 (coalesced), kept for epilogues ----
  {
    const float4* z4 = (const float4*)(z_e + zbase);
    #pragma unroll
    for (int it = 0; it < 4; ++it) {
      const int f  = tid + it * 256;
      const int d  = f >> 4;
      const int r4 = f & 15;
      const float4 v = z4[(size_t)d * 1024 + r4];
      *(float4*)(z_lds + d * ZP + r4 * 4) = v;
    }
  }
  __syncthreads();

  // ---- build B-frags (z in fp16 regs) + exact row norm zz ----
  f16x8 bf0, bf1;
  float zz = 0.f;
  #pragma unroll
  for (int j = 0; j < 8; ++j) {
    const float v0 = z_lds[(q * 8 + j) * ZP + rloc];        // d = q*8+j
    const float v1 = z_lds[(32 + q * 8 + j) * ZP + rloc];   // d = 32+q*8+j
    zz = fmaf(v0, v0, zz);
    zz = fmaf(v1, v1, zz);
    bf0[j] = (f16)v0;
    bf1[j] = (f16)v1;
  }
  zz += __shfl_xor(zz, 16, 64);
  zz += __shfl_xor(zz, 32, 64);   // all lanes: zz of row (lane&15)

  // A-frag per-lane swizzled byte offsets: code (lane&15), dblk kh*4+q
  const int lcl7  = m & 7;
  const int aoff0 = m * 128 + ((q)     ^ lcl7) * 16;
  const int aoff1 = m * 128 + ((4 + q) ^ lcl7) * 16;

  float m1 = INFINITY, m2 = INFINITY;
  int   i1 = 0;
  float emax = 0.f;   // tracked by staging threads tid<32

  const float4* e16g4 = (const float4*)e16gf;
  const float4* eNg4  = (const float4*)eN;

  #pragma unroll 1
  for (int c = 0; c < 8; ++c) {
    __syncthreads();   // previous chunk's e_lds reads done
    // stage 128 codes x 64d fp16, XOR-swizzle 16B units within each row
    #pragma unroll
    for (int i = 0; i < 4; ++i) {
      const int u  = i * 256 + tid;   // 0..1023 16B-units
      const int cl = u >> 3;          // local code
      const int db = u & 7;           // logical dblk
      const float4 v = e16g4[c * 1024 + u];
      *(float4*)((char*)e_lds + cl * 128 + ((db ^ (cl & 7)) * 16)) = v;
    }
    if (tid < 32) {
      const float4 v = eNg4[c * 32 + tid];
      ((float4*)en_lds)[tid] = v;
      emax = fmaxf(emax, fmaxf(fmaxf(v.x, v.y), fmaxf(v.z, v.w)));
    }
    __syncthreads();

    #pragma unroll
    for (int t = 0; t < 8; ++t) {
      const f16x8 a0 = *(const f16x8*)((const char*)e_lds + t * 2048 + aoff0);
      const f16x8 a1 = *(const f16x8*)((const char*)e_lds + t * 2048 + aoff1);
      f32x4 acc = {0.f, 0.f, 0.f, 0.f};
      acc = __builtin_amdgcn_mfma_f32_16x16x32_f16(a0, bf0, acc, 0, 0, 0);
      acc = __builtin_amdgcn_mfma_f32_16x16x32_f16(a1, bf1, acc, 0, 0, 0);
      const float4 en4 = *(const float4*)(en_lds + t * 16 + q * 4);
      const float env[4] = {en4.x, en4.y, en4.z, en4.w};
      const int ib = c * 128 + t * 16 + q * 4;
      #pragma unroll
      for (int r = 0; r < 4; ++r) {
        const float v  = fmaf(-2.f, acc[r], env[r]);
        const bool lt  = v < m1;
        m2 = fminf(m2, fmaxf(v, m1));   // uses old m1
        if (lt) i1 = ib + r;
        m1 = fminf(m1, v);
      }
    }
  }

  // ---- block max of eNorm (for margin) ----
  __syncthreads();
  if (tid < 32) sred[tid] = emax;
  __syncthreads();
  if (tid == 0) {
    float mx = sred[0];
    #pragma unroll
    for (int i2 = 1; i2 < 32; ++i2) mx = fmaxf(mx, sred[i2]);
    sred[32] = mx;
  }
  __syncthreads();
  const float emax2 = sred[32];

  // ---- merge (m1,i1,m2) across the 4 code-subgroups ----
  #pragma unroll
  for (int off = 16; off <= 32; off <<= 1) {
    const float m1o = __shfl_xor(m1, off, 64);
    const float m2o = __shfl_xor(m2, off, 64);
    const int   i1o = __shfl_xor(i1, off, 64);
    const float nm2 = fminf(fminf(m2, m2o), fmaxf(m1, m1o));
    if (m1o < m1) i1 = i1o;
    m1 = fminf(m1, m1o);
    m2 = nm2;
  }

  if (lane < 16) {   // one writer per row
    const int row = rloc;
    const float M = 0.00390625f * sqrtf(zz) * sqrtf(emax2);  // 2^-8*||z||*Emax
    if (m2 - m1 > M) {
      bidx[row] = i1;
      out[O_IDX + n0 + row] = (float)i1;
      atomicAdd(cnt + i1, 1.0f);
    } else {
      bidx[row] = -1;                       // defer to exact rescore
      const int s = atomicAdd(flagn, 1);
      flagl[s] = n0 + row;
    }
  }
  __syncthreads();

  // ---- epilogue A: z_q = z + (e - z); coalesced stores over rows ----
  {
    const int row  = tid & 63;
    const int dgrp = tid >> 6;          // 4 groups x 16 d
    const int code = bidx[row];
    if (code >= 0) {
      const float4* er4 = (const float4*)(embT + (size_t)code * 64);
      #pragma unroll
      for (int qq = 0; qq < 4; ++qq) {
        const float4 e4 = er4[dgrp * 4 + qq];
        const float ev[4] = {e4.x, e4.y, e4.z, e4.w};
        #pragma unroll
        for (int x = 0; x < 4; ++x) {
          const int d = dgrp * 16 + qq * 4 + x;
          const float zv = z_lds[d * ZP + row];
          out[O_ZQ + zbase + (size_t)d * 4096 + row] = zv + (ev[x] - zv);
        }
      }
    }
  }

  // ---- epilogue B: segment-sum; one coalesced atomic instr per row ----
  {
    #pragma unroll 4
    for (int rr = 0; rr < 16; ++rr) {
      const int row  = wv * 16 + rr;
      const int code = bidx[row];
      if (code >= 0)
        atomicAdd(upd + (size_t)code * 64 + lane, z_lds[lane * ZP + row]);
    }
  }
}

// ---------------------------------------------------------------------------
// K3: exact fp32 rescore of ambiguous rows (gap <= margin). 16-row batches
// per block so embT is read once per batch (L2-resident). Thread t: row t&15,
// codes (t>>4)*64..+63; z row held in regs; ascending-code strict-< argmin
// reproduces the reference lowest-index tie rule. Completes all side effects.
__global__ __launch_bounds__(256) void vq_rescore(
    const float* __restrict__ z_e,
    const float* __restrict__ embT,
    const float* __restrict__ eN,
    const int* __restrict__ flagn,
    const int* __restrict__ flagl,
    float* __restrict__ upd,
    float* __restrict__ cnt,
    float* __restrict__ out) {
  __shared__ float z_l[16][ZP];
  __shared__ float rv[256];
  __shared__ int   ri[256];
  __shared__ int   rowids[16];
  __shared__ int   best[16];

  const int tid = threadIdx.x;
  const int nf  = *flagn;
  const int nb  = (nf + 15) >> 4;

  for (int bt = blockIdx.x; bt < nb; bt += gridDim.x) {
    __syncthreads();   // protect LDS reuse across batches
    if (tid < 16) {
      const int j = bt * 16 + tid;
      rowids[tid] = (j < nf) ? flagl[j] : -1;
    }
    __syncthreads();
    // stage z rows
    {
      const int r  = tid >> 4;
      const int dg = tid & 15;
      const int rowid = rowids[r];
      if (rowid >= 0) {
        const int bb = rowid >> 12;
        const int hw = rowid & 4095;
        const size_t base = (size_t)bb * 262144 + hw;
        #pragma unroll
        for (int x = 0; x < 4; ++x) {
          const int d = dg * 4 + x;
          z_l[r][d] = z_e[base + (size_t)d * 4096];
        }
      }
    }
    __syncthreads();
    // exact distances
    {
      const int r = tid & 15;
      const int g = tid >> 4;
      float zreg[64];
      #pragma unroll
      for (int d4 = 0; d4 < 16; ++d4) {
        const float4 zv = *(const float4*)(&z_l[r][d4 * 4]);
        zreg[d4 * 4 + 0] = zv.x; zreg[d4 * 4 + 1] = zv.y;
        zreg[d4 * 4 + 2] = zv.z; zreg[d4 * 4 + 3] = zv.w;
      }
      float bm = INFINITY; int bi = 0;
      #pragma unroll 1
      for (int cc = 0; cc < 64; ++cc) {
        const int k = g * 64 + cc;
        const float4* e4p = (const float4*)(embT + (size_t)k * 64);
        float a0 = 0.f, a1 = 0.f, a2 = 0.f, a3 = 0.f;
        #pragma unroll
        for (int d4 = 0; d4 < 16; ++d4) {
          const float4 e4 = e4p[d4];
          a0 = fmaf(zreg[d4 * 4 + 0], e4.x, a0);
          a1 = fmaf(zreg[d4 * 4 + 1], e4.y, a1);
          a2 = fmaf(zreg[d4 * 4 + 2], e4.z, a2);
          a3 = fmaf(zreg[d4 * 4 + 3], e4.w, a3);
        }
        const float dist = fmaf(-2.f, (a0 + a1) + (a2 + a3), eN[k]);
        if (dist < bm) { bm = dist; bi = k; }
      }
      rv[tid] = bm; ri[tid] = bi;
    }
    __syncthreads();
    if (tid < 16) {
      const int r = tid;
      if (rowids[r] >= 0) {
        float bm = INFINITY; int bi = 0;
        #pragma unroll
        for (int g = 0; g < 16; ++g) {
          const float v = rv[g * 16 + r];
          if (v < bm) { bm = v; bi = ri[g * 16 + r]; }
        }
        best[r] = bi;
        out[O_IDX + rowids[r]] = (float)bi;
        atomicAdd(cnt + bi, 1.0f);
      }
    }
    __syncthreads();
    // epilogue: z_q + segment-sum for rescued rows
    {
      const int r  = tid >> 4;
      const int dg = tid & 15;
      const int rowid = rowids[r];
      if (rowid >= 0) {
        const int code = best[r];
        const int bb = rowid >> 12;
        const int hw = rowid & 4095;
        const size_t base = (size_t)bb * 262144 + hw;
        #pragma unroll
        for (int x = 0; x < 4; ++x) {
          const int d  = dg * 4 + x;
          const float zv = z_l[r][d];
          const float ev = embT[(size_t)code * 64 + d];
          out[O_ZQ + base + (size_t)d * 4096] = zv + (ev - zv);
          atomicAdd(upd + (size_t)code * 64 + d, zv);
        }
      }
    }
  }
}

// ---------------------------------------------------------------------------
// K4: EMA updates + normalization. Each block redundantly reduces n.
__global__ __launch_bounds__(256) void vq_final(const float* __restrict__ emb_ema,
                                                const float* __restrict__ counts_ema,
                                                const float* __restrict__ ws,
                                                float* __restrict__ out) {
  __shared__ float red[256];
  const int tid = threadIdx.x;
  const float* cnt = ws + W_CNT;

  float psum = 0.f;
  for (int t = tid; t < KCODES; t += 256) {
    const float ce  = counts_ema[t];
    const float cen = ce + 0.01f * (cnt[t] - ce);
    psum += cen;
    if (blockIdx.x == 0) out[O_CEN + t] = cen;
  }
  red[tid] = psum;
  __syncthreads();
  #pragma unroll
  for (int s = 128; s > 0; s >>= 1) {
    if (tid < s) red[tid] += red[tid + s];
    __syncthreads();
  }
  const float nsum = red[0];

  const int i = blockIdx.x * 256 + tid;   // 0..65535 over [D][K]
  const int d = i >> 10;
  const int k = i & 1023;

  const float ce  = counts_ema[k];
  const float cen = ce + 0.01f * (cnt[k] - ce);
  const float norm = (cen + 1e-5f) / (nsum + (float)KCODES * 1e-5f) * nsum;

  const float ema     = emb_ema[i];
  const float ema_new = ema + 0.01f * (ws[W_UPD + (size_t)k * 64 + d] - ema);
  out[O_EMA + i] = ema_new;
  out[O_EMB + i] = ema_new / norm;
}

// ---------------------------------------------------------------------------
extern "C" void kernel_launch(void* const* d_in, const int* in_sizes, int n_in,
                              void* d_out, int out_size, void* d_ws, size_t ws_size,
                              hipStream_t stream) {
  const float* z_e        = (const float*)d_in[0];
  const float* emb        = (const float*)d_in[1];
  const float* emb_ema    = (const float*)d_in[2];
  const float* counts_ema = (const float*)d_in[3];
  float* out = (float*)d_out;
  float* ws  = (float*)d_ws;

  vq_prep<<<16, 256, 0, stream>>>(emb, ws);
  vq_main<<<1024, 256, 0, stream>>>(z_e, ws + W_E16, ws + W_EMBT, ws + W_ENORM,
                                    ws + W_UPD, ws + W_CNT,
                                    (int*)(ws + W_FLAGN), (int*)(ws + W_FLAGL), out);
  vq_rescore<<<256, 256, 0, stream>>>(z_e, ws + W_EMBT, ws + W_ENORM,
                                      (int*)(ws + W_FLAGN), (int*)(ws + W_FLAGL),
                                      ws + W_UPD, ws + W_CNT, out);
  vq_final<<<256, 256, 0, stream>>>(emb_ema, counts_ema, ws, out);
}

// Round 2
// 154.711 us; speedup vs baseline: 1.5312x; 1.5312x over previous
//
#include <hip/hip_runtime.h>
#include <math.h>

// Problem constants
#define KCODES 1024
#define DDIM   64

// Output layout (floats), concatenated in reference return order:
// z_q_out [16,64,64,64], idx_out [16,64,64], emb_new [64,1024],
// emb_ema_new [64,1024], counts_ema_new [1024]
constexpr size_t O_ZQ  = 0;
constexpr size_t O_IDX = 4194304;
constexpr size_t O_EMB = O_IDX + 65536;   // 4259840
constexpr size_t O_EMA = O_EMB + 65536;   // 4325376
constexpr size_t O_CEN = O_EMA + 65536;   // 4390912

// Workspace layout (float offsets)
constexpr size_t W_UPD   = 0;               // [K][D] segment-sum accumulator
constexpr size_t W_CNT   = 65536;           // [K] histogram
constexpr size_t W_ENORM = W_CNT + 1024;    // [K] ||e_k||^2 (fp32 exact)
constexpr size_t W_EMBT  = W_ENORM + 1024;  // [K][D] transposed codebook fp32
constexpr size_t W_E16   = W_EMBT + 65536;  // [K][D] codebook hi f16 (32768 floats)
constexpr size_t W_E16L  = W_E16 + 32768;   // [K][D] codebook lo f16 (32768 floats)
constexpr size_t W_FLAGN = W_E16L + 32768;  // 1 int: count of ambiguous rows (+pad)
constexpr size_t W_FLAGL = W_FLAGN + 16;    // [FLAGCAP] int row ids
constexpr int    FLAGCAP = 16384;

typedef _Float16 f16;
typedef f16 f16x8 __attribute__((ext_vector_type(8)));
typedef float f32x4 __attribute__((ext_vector_type(4)));

// ---------------------------------------------------------------------------
// K1: LDS-tiled transpose emb[D][K] -> embT[K][D] (fp32 + f16 hi/lo split),
// eNorm, zero W_UPD/W_CNT/flag counter. 16 blocks; block g: codes g*64..+63.
__global__ __launch_bounds__(256) void vq_prep(const float* __restrict__ emb,
                                               float* __restrict__ ws) {
  __shared__ float t_lds[64 * 65];          // [d][k] padded (+1)
  const int tid = threadIdx.x;
  const int g   = blockIdx.x;
  const int k0  = g * 64;

  #pragma unroll
  for (int it = 0; it < 16; ++it) {
    const int idx = tid + it * 256;         // 0..4095
    const int d   = idx >> 6;
    const int kq  = idx & 63;
    t_lds[d * 65 + kq] = emb[d * KCODES + k0 + kq];
  }
  __syncthreads();

  f16* e16h = (f16*)(ws + W_E16);
  f16* e16l = (f16*)(ws + W_E16L);
  #pragma unroll
  for (int it = 0; it < 16; ++it) {
    const int idx = tid + it * 256;
    const int k   = idx >> 6;
    const int d   = idx & 63;
    const float v = t_lds[d * 65 + k];
    ws[W_EMBT + (size_t)(k0 + k) * 64 + d] = v;
    const f16 hi = (f16)v;
    e16h[(size_t)(k0 + k) * 64 + d] = hi;
    e16l[(size_t)(k0 + k) * 64 + d] = (f16)(v - (float)hi);
  }

  if (tid < 64) {
    const int k = tid;
    float s = 0.f;
    #pragma unroll
    for (int d = 0; d < DDIM; ++d) {
      const float v = t_lds[d * 65 + k];
      s = fmaf(v, v, s);
    }
    ws[W_ENORM + k0 + k] = s;
  }

  float4* u4 = (float4*)(ws + W_UPD);
  #pragma unroll
  for (int j = 0; j < 4; ++j) u4[g * 1024 + tid + j * 256] = float4{0.f, 0.f, 0.f, 0.f};
  if (tid < 64) ws[W_CNT + k0 + tid] = 0.f;
  if (g == 0 && tid == 0) ((int*)(ws + W_FLAGN))[0] = 0;
}

// ---------------------------------------------------------------------------
// K2: MFMA distance GEMM (3-term f16 split) + certified argmin + epilogue.
// 1024 blocks x 256 threads; block = 64 rows x full K.
// z = zh+zl, e = eh+el (residuals capture to 2^-22 rel); dot = zh.eh + zh.el
// + zl.eh via 6 chained mfma_16x16x32_f16 per 16-code tile (products exact
// in f32). Worst-case gap error <= ~5.2e-5 * ||z|| * Emax (dropped zl.el +
// 192 f32 accum roundings). Accept argmin iff m2-m1 > 1e-4*||z||*Emax (1.9x
// safety); else defer row to exact fp32 rescore (K3).
#define ZP 68
__global__ __launch_bounds__(256, 4) void vq_main(
    const float* __restrict__ z_e,
    const float* __restrict__ e16hf,  // ws + W_E16  (f16 hi [K][64])
    const float* __restrict__ e16lf,  // ws + W_E16L (f16 lo [K][64])
    const float* __restrict__ embT,   // ws + W_EMBT [K][D] fp32 (epilogue A)
    const float* __restrict__ eN,     // ws + W_ENORM [K]
    float* __restrict__ upd,          // ws + W_UPD   [K][D]
    float* __restrict__ cnt,          // ws + W_CNT   [K]
    int*   __restrict__ flagn,
    int*   __restrict__ flagl,
    float* __restrict__ out) {
  __shared__ float z_lds[DDIM * ZP];             // [d][row] padded, fp32
  __shared__ __align__(16) f16 e_lds[128 * 64];  // chunk hi, swizzled
  __shared__ __align__(16) f16 el_lds[128 * 64]; // chunk lo, swizzled
  __shared__ __align__(16) float en_lds[128];
  __shared__ int   bidx[64];
  __shared__ float sred[33];

  const int tid  = threadIdx.x;
  const int bid  = blockIdx.x;
  const int wv   = tid >> 6;
  const int lane = tid & 63;
  const int m    = lane & 15;        // A-row supplier / C col (z row)
  const int q    = lane >> 4;        // k-subgroup / C code-subgroup
  const int rloc = wv * 16 + m;      // this lane's z row within block

  const int n0  = bid * 64;
  const int b   = n0 >> 12;
  const int hw0 = n0 & 4095;
  const size_t zbase = (size_t)b * 262144 + (size_t)hw0;

  // ---- stage z tile [64d][64r] fp32 (coalesced), kept for epilogues ----
  {
    const float4* z4 = (const float4*)(z_e + zbase);
    #pragma unroll
    for (int it = 0; it < 4; ++it) {
      const int f  = tid + it * 256;
      const int d  = f >> 4;
      const int r4 = f & 15;
      const float4 v = z4[(size_t)d * 1024 + r4];
      *(float4*)(z_lds + d * ZP + r4 * 4) = v;
    }
  }
  __syncthreads();

  // ---- build B-frags hi/lo (z split) + exact row norm zz ----
  f16x8 bf0h, bf1h, bf0l, bf1l;
  float zz = 0.f;
  #pragma unroll
  for (int j = 0; j < 8; ++j) {
    const float v0 = z_lds[(q * 8 + j) * ZP + rloc];        // d = q*8+j
    const float v1 = z_lds[(32 + q * 8 + j) * ZP + rloc];   // d = 32+q*8+j
    zz = fmaf(v0, v0, zz);
    zz = fmaf(v1, v1, zz);
    const f16 h0 = (f16)v0;
    const f16 h1 = (f16)v1;
    bf0h[j] = h0;
    bf1h[j] = h1;
    bf0l[j] = (f16)(v0 - (float)h0);
    bf1l[j] = (f16)(v1 - (float)h1);
  }
  zz += __shfl_xor(zz, 16, 64);
  zz += __shfl_xor(zz, 32, 64);   // all lanes: zz of row (lane&15)

  // A-frag per-lane swizzled byte offsets: code (lane&15), dblk kh*4+q
  const int lcl7  = m & 7;
  const int aoff0 = m * 128 + ((q)     ^ lcl7) * 16;
  const int aoff1 = m * 128 + ((4 + q) ^ lcl7) * 16;

  float m1 = INFINITY, m2 = INFINITY;
  int   i1 = 0;
  float emax = 0.f;   // tracked by staging threads tid<32

  const float4* e16g4h = (const float4*)e16hf;
  const float4* e16g4l = (const float4*)e16lf;
  const float4* eNg4   = (const float4*)eN;

  #pragma unroll 1
  for (int c = 0; c < 8; ++c) {
    __syncthreads();   // previous chunk's e_lds reads done
    // stage 128 codes x 64d f16 hi+lo, XOR-swizzle 16B units within rows
    #pragma unroll
    for (int i = 0; i < 4; ++i) {
      const int u  = i * 256 + tid;   // 0..1023 16B-units
      const int cl = u >> 3;          // local code
      const int db = u & 7;           // logical dblk
      const int so = cl * 128 + ((db ^ (cl & 7)) * 16);
      const float4 vh = e16g4h[c * 1024 + u];
      const float4 vl = e16g4l[c * 1024 + u];
      *(float4*)((char*)e_lds  + so) = vh;
      *(float4*)((char*)el_lds + so) = vl;
    }
    if (tid < 32) {
      const float4 v = eNg4[c * 32 + tid];
      ((float4*)en_lds)[tid] = v;
      emax = fmaxf(emax, fmaxf(fmaxf(v.x, v.y), fmaxf(v.z, v.w)));
    }
    __syncthreads();

    #pragma unroll
    for (int t = 0; t < 8; ++t) {
      const f16x8 a0h = *(const f16x8*)((const char*)e_lds  + t * 2048 + aoff0);
      const f16x8 a1h = *(const f16x8*)((const char*)e_lds  + t * 2048 + aoff1);
      const f16x8 a0l = *(const f16x8*)((const char*)el_lds + t * 2048 + aoff0);
      const f16x8 a1l = *(const f16x8*)((const char*)el_lds + t * 2048 + aoff1);
      f32x4 acc = {0.f, 0.f, 0.f, 0.f};
      acc = __builtin_amdgcn_mfma_f32_16x16x32_f16(a0l, bf0h, acc, 0, 0, 0);
      acc = __builtin_amdgcn_mfma_f32_16x16x32_f16(a1l, bf1h, acc, 0, 0, 0);
      acc = __builtin_amdgcn_mfma_f32_16x16x32_f16(a0h, bf0l, acc, 0, 0, 0);
      acc = __builtin_amdgcn_mfma_f32_16x16x32_f16(a1h, bf1l, acc, 0, 0, 0);
      acc = __builtin_amdgcn_mfma_f32_16x16x32_f16(a0h, bf0h, acc, 0, 0, 0);
      acc = __builtin_amdgcn_mfma_f32_16x16x32_f16(a1h, bf1h, acc, 0, 0, 0);
      const float4 en4 = *(const float4*)(en_lds + t * 16 + q * 4);
      const float env[4] = {en4.x, en4.y, en4.z, en4.w};
      const int ib = c * 128 + t * 16 + q * 4;
      #pragma unroll
      for (int r = 0; r < 4; ++r) {
        const float v  = fmaf(-2.f, acc[r], env[r]);
        const bool lt  = v < m1;
        m2 = fminf(m2, fmaxf(v, m1));   // uses old m1
        if (lt) i1 = ib + r;
        m1 = fminf(m1, v);
      }
    }
  }

  // ---- block max of eNorm (for margin) ----
  __syncthreads();
  if (tid < 32) sred[tid] = emax;
  __syncthreads();
  if (tid == 0) {
    float mx = sred[0];
    #pragma unroll
    for (int i2 = 1; i2 < 32; ++i2) mx = fmaxf(mx, sred[i2]);
    sred[32] = mx;
  }
  __syncthreads();
  const float emax2 = sred[32];

  // ---- merge (m1,i1,m2) across the 4 code-subgroups ----
  #pragma unroll
  for (int off = 16; off <= 32; off <<= 1) {
    const float m1o = __shfl_xor(m1, off, 64);
    const float m2o = __shfl_xor(m2, off, 64);
    const int   i1o = __shfl_xor(i1, off, 64);
    const float nm2 = fminf(fminf(m2, m2o), fmaxf(m1, m1o));
    if (m1o < m1) i1 = i1o;
    m1 = fminf(m1, m1o);
    m2 = nm2;
  }

  if (lane < 16) {   // one writer per row
    const int row = rloc;
    const float M = 1.0e-4f * sqrtf(zz) * sqrtf(emax2);
    if (m2 - m1 > M) {
      bidx[row] = i1;
      out[O_IDX + n0 + row] = (float)i1;
      atomicAdd(cnt + i1, 1.0f);
    } else {
      bidx[row] = -1;                       // defer to exact rescore
      const int s = atomicAdd(flagn, 1);
      if (s < FLAGCAP) flagl[s] = n0 + row;
    }
  }
  __syncthreads();

  // ---- epilogue A: z_q = z + (e - z); coalesced stores over rows ----
  {
    const int row  = tid & 63;
    const int dgrp = tid >> 6;          // 4 groups x 16 d
    const int code = bidx[row];
    if (code >= 0) {
      const float4* er4 = (const float4*)(embT + (size_t)code * 64);
      #pragma unroll
      for (int qq = 0; qq < 4; ++qq) {
        const float4 e4 = er4[dgrp * 4 + qq];
        const float ev[4] = {e4.x, e4.y, e4.z, e4.w};
        #pragma unroll
        for (int x = 0; x < 4; ++x) {
          const int d = dgrp * 16 + qq * 4 + x;
          const float zv = z_lds[d * ZP + row];
          out[O_ZQ + zbase + (size_t)d * 4096 + row] = zv + (ev[x] - zv);
        }
      }
    }
  }

  // ---- epilogue B: segment-sum; one coalesced atomic instr per row ----
  {
    #pragma unroll 4
    for (int rr = 0; rr < 16; ++rr) {
      const int row  = wv * 16 + rr;
      const int code = bidx[row];
      if (code >= 0)
        atomicAdd(upd + (size_t)code * 64 + lane, z_lds[lane * ZP + row]);
    }
  }
}

// ---------------------------------------------------------------------------
// K3: exact fp32 rescore, ONE ROW PER BLOCK (codes-parallel: 256 threads x 4
// contiguous codes, 64 independent float4 loads issued together -> one
// latency exposure). Lexicographic (dist, idx) reduction reproduces the
// reference lowest-index tie rule. Completes idx/z_q/hist/segment-sum.
__global__ __launch_bounds__(256) void vq_rescore(
    const float* __restrict__ z_e,
    const float* __restrict__ embT,
    const float* __restrict__ eN,
    const int* __restrict__ flagn,
    const int* __restrict__ flagl,
    float* __restrict__ upd,
    float* __restrict__ cnt,
    float* __restrict__ out) {
  __shared__ float zrow[64];
  __shared__ float wv_v[4];
  __shared__ int   wv_i[4];
  __shared__ int   bestc;

  const int tid = threadIdx.x;
  int nf = *flagn;
  if (nf > FLAGCAP) nf = FLAGCAP;

  for (int j = blockIdx.x; j < nf; j += gridDim.x) {
    __syncthreads();   // protect zrow/bestc reuse across iterations
    const int rowid = flagl[j];
    const int bb = rowid >> 12;
    const int hw = rowid & 4095;
    const size_t base = (size_t)bb * 262144 + (size_t)hw;
    if (tid < 64) zrow[tid] = z_e[base + (size_t)tid * 4096];
    __syncthreads();

    // 4 ascending codes per thread; strict < keeps lowest index
    float bm = INFINITY;
    int   bi = 0;
    #pragma unroll
    for (int cc = 0; cc < 4; ++cc) {
      const int k = tid * 4 + cc;
      const float4* e4p = (const float4*)(embT + (size_t)k * 64);
      float a0 = 0.f, a1 = 0.f, a2 = 0.f, a3 = 0.f;
      #pragma unroll
      for (int d4 = 0; d4 < 16; ++d4) {
        const float4 e4 = e4p[d4];
        a0 = fmaf(zrow[d4 * 4 + 0], e4.x, a0);
        a1 = fmaf(zrow[d4 * 4 + 1], e4.y, a1);
        a2 = fmaf(zrow[d4 * 4 + 2], e4.z, a2);
        a3 = fmaf(zrow[d4 * 4 + 3], e4.w, a3);
      }
      const float dist = fmaf(-2.f, (a0 + a1) + (a2 + a3), eN[k]);
      if (dist < bm) { bm = dist; bi = k; }
    }
    // wave lexicographic reduce
    #pragma unroll
    for (int mm = 1; mm < 64; mm <<= 1) {
      const float v2 = __shfl_xor(bm, mm, 64);
      const int   i2 = __shfl_xor(bi, mm, 64);
      if (v2 < bm || (v2 == bm && i2 < bi)) { bm = v2; bi = i2; }
    }
    if ((tid & 63) == 0) { wv_v[tid >> 6] = bm; wv_i[tid >> 6] = bi; }
    __syncthreads();
    if (tid == 0) {
      float v = wv_v[0]; int ix = wv_i[0];
      #pragma unroll
      for (int w = 1; w < 4; ++w) {
        if (wv_v[w] < v || (wv_v[w] == v && wv_i[w] < ix)) { v = wv_v[w]; ix = wv_i[w]; }
      }
      bestc = ix;
      out[O_IDX + rowid] = (float)ix;
      atomicAdd(cnt + ix, 1.0f);
    }
    __syncthreads();
    if (tid < 64) {
      const int d = tid;
      const float zv = zrow[d];
      const float ev = embT[(size_t)bestc * 64 + d];
      out[O_ZQ + base + (size_t)d * 4096] = zv + (ev - zv);
      atomicAdd(upd + (size_t)bestc * 64 + d, zv);
    }
  }
}

// ---------------------------------------------------------------------------
// K4: EMA updates + normalization. Each block redundantly reduces n.
__global__ __launch_bounds__(256) void vq_final(const float* __restrict__ emb_ema,
                                                const float* __restrict__ counts_ema,
                                                const float* __restrict__ ws,
                                                float* __restrict__ out) {
  __shared__ float red[256];
  const int tid = threadIdx.x;
  const float* cnt = ws + W_CNT;

  float psum = 0.f;
  for (int t = tid; t < KCODES; t += 256) {
    const float ce  = counts_ema[t];
    const float cen = ce + 0.01f * (cnt[t] - ce);
    psum += cen;
    if (blockIdx.x == 0) out[O_CEN + t] = cen;
  }
  red[tid] = psum;
  __syncthreads();
  #pragma unroll
  for (int s = 128; s > 0; s >>= 1) {
    if (tid < s) red[tid] += red[tid + s];
    __syncthreads();
  }
  const float nsum = red[0];

  const int i = blockIdx.x * 256 + tid;   // 0..65535 over [D][K]
  const int d = i >> 10;
  const int k = i & 1023;

  const float ce  = counts_ema[k];
  const float cen = ce + 0.01f * (cnt[k] - ce);
  const float norm = (cen + 1e-5f) / (nsum + (float)KCODES * 1e-5f) * nsum;

  const float ema     = emb_ema[i];
  const float ema_new = ema + 0.01f * (ws[W_UPD + (size_t)k * 64 + d] - ema);
  out[O_EMA + i] = ema_new;
  out[O_EMB + i] = ema_new / norm;
}

// ---------------------------------------------------------------------------
extern "C" void kernel_launch(void* const* d_in, const int* in_sizes, int n_in,
                              void* d_out, int out_size, void* d_ws, size_t ws_size,
                              hipStream_t stream) {
  const float* z_e        = (const float*)d_in[0];
  const float* emb        = (const float*)d_in[1];
  const float* emb_ema    = (const float*)d_in[2];
  const float* counts_ema = (const float*)d_in[3];
  float* out = (float*)d_out;
  float* ws  = (float*)d_ws;

  vq_prep<<<16, 256, 0, stream>>>(emb, ws);
  vq_main<<<1024, 256, 0, stream>>>(z_e, ws + W_E16, ws + W_E16L,
                                    ws + W_EMBT, ws + W_ENORM,
                                    ws + W_UPD, ws + W_CNT,
                                    (int*)(ws + W_FLAGN), (int*)(ws + W_FLAGL), out);
  vq_rescore<<<1024, 256, 0, stream>>>(z_e, ws + W_EMBT, ws + W_ENORM,
                                       (int*)(ws + W_FLAGN), (int*)(ws + W_FLAGL),
                                       ws + W_UPD, ws + W_CNT, out);
  vq_final<<<256, 256, 0, stream>>>(emb_ema, counts_ema, ws, out);
}